// Round 1
// 310.899 us; speedup vs baseline: 1.0027x; 1.0027x over previous
//
#include <hip/hip_runtime.h>
#include <cstdint>
#include <cstddef>

// ForwardAttention: B=32, T=2048, Q=K=V=512, A=128, TEMP=1
// d_out = [context 32x512 | fw 32x2048] f32  (81920 floats)
//
// Pipeline (v2: softmax fused into context kernel):
//  1) prep:      qp = query@Wq (fp32), WkT = bf16(Wk^T) [128][512]        -> ws
//  2) energy:    bf16 MFMA GEMM keys@Wk fused tanh/We epilogue            -> ws energy
//  3) ctx_fused: per (b,t-chunk) block: replicated masked softmax +
//                forward reweight (bit-identical to v1) in LDS, write own
//                fw chunk to d_out, then context partial over own chunk   -> ws part
//  4) ctx_reduce: sum partials -> context region of d_out

#define T_ 2048
#define KD 512
#define AD 128

typedef __attribute__((ext_vector_type(8))) short bf16x8;
typedef __attribute__((ext_vector_type(4))) float f32x4;

__device__ __forceinline__ unsigned pack2bf(float a, float b) {
    unsigned ua = __float_as_uint(a), ub = __float_as_uint(b);
    ua += 0x7FFFu + ((ua >> 16) & 1u);   // RNE
    ub += 0x7FFFu + ((ub >> 16) & 1u);
    return (ua >> 16) | (ub & 0xFFFF0000u);
}

// ---------------- kernel 1: qp + WkT(bf16) prep ----------------
__global__ __launch_bounds__(256) void prep_kernel(
    const float* __restrict__ query, const float* __restrict__ Wq,
    const float* __restrict__ Wk, float* __restrict__ qp,
    unsigned short* __restrict__ WkT)
{
    __shared__ float sq[128];
    const int tid = threadIdx.x;
    if (blockIdx.x < 32) {
        // qp[b][a] = sum_k query[b][k] * Wq[k][a], fp32 exact
        const int b = blockIdx.x;
        const int a = tid & 127, half = tid >> 7;
        const float* q = query + (size_t)b * KD + half * 256;
        const float* w = Wq + (size_t)(half * 256) * AD + a;
        float s0 = 0.f, s1 = 0.f, s2 = 0.f, s3 = 0.f;
        #pragma unroll 4
        for (int k = 0; k < 256; k += 4) {
            s0 += q[k + 0] * w[(size_t)(k + 0) * AD];
            s1 += q[k + 1] * w[(size_t)(k + 1) * AD];
            s2 += q[k + 2] * w[(size_t)(k + 2) * AD];
            s3 += q[k + 3] * w[(size_t)(k + 3) * AD];
        }
        float s = (s0 + s1) + (s2 + s3);
        if (half == 0) sq[a] = s;
        __syncthreads();
        if (half == 1) qp[(size_t)b * AD + a] = sq[a] + s;
    } else {
        // WkT[n][k] = bf16(Wk[k][n]); coalesced reads of Wk rows
        const int blk2 = blockIdx.x - 32;      // 0..31, 16 k-rows each
        const int n = tid & 127, kr = tid >> 7;
        #pragma unroll
        for (int kk = 0; kk < 8; kk++) {
            int k = blk2 * 16 + kr * 8 + kk;
            float v = Wk[(size_t)k * AD + n];
            unsigned u = __float_as_uint(v);
            u += 0x7FFFu + ((u >> 16) & 1u);
            WkT[(size_t)n * KD + k] = (unsigned short)(u >> 16);
        }
    }
}

// ---------------- kernel 2: energies via bf16 MFMA ----------------
// Global GEMM: M=65536 (b*2048+t), K=512, N=128. Block: BM=128, BK=32, full N.
// Epilogue: energy[m] = sum_a We[a]*tanh(kp[m][a] + qp[b][a])
// HBM-bound on keys (134 MB); writes energies to workspace (NOT d_out) so
// the fused softmax/context kernel can read all chunks race-free.
__global__ __launch_bounds__(256, 2) void energy_kernel(
    const float* __restrict__ keys, const unsigned short* __restrict__ WkT,
    const float* __restrict__ qp, const float* __restrict__ We,
    float* __restrict__ energy)
{
    __shared__ __align__(16) unsigned short sA[128 * 40];  // [m][k], pad->40
    __shared__ __align__(16) unsigned short sB[128 * 40];  // [n][k], pad->40
    const int tid = threadIdx.x;
    const int m0 = blockIdx.x * 128;
    const int b = m0 >> 11;

    const int row = tid >> 1, half = tid & 1;   // staging: 2 threads/row, 16 elems each
    const float* gA = keys + (size_t)(m0 + row) * KD + half * 16;
    const unsigned short* gB = WkT + (size_t)row * KD + half * 16;
    unsigned short* dA = &sA[row * 40 + half * 16];
    unsigned short* dB = &sB[row * 40 + half * 16];

    const int lane = tid & 63, wv = tid >> 6;
    const int lr = lane & 15, quad = lane >> 4;

    f32x4 acc[2][8];
    #pragma unroll
    for (int mt = 0; mt < 2; mt++)
        #pragma unroll
        for (int nt = 0; nt < 8; nt++)
            acc[mt][nt] = (f32x4){0.f, 0.f, 0.f, 0.f};

    for (int k0 = 0; k0 < KD; k0 += 32) {
        // stage A: fp32 -> bf16
        float4 f0 = *(const float4*)(gA + k0 + 0);
        float4 f1 = *(const float4*)(gA + k0 + 4);
        float4 f2 = *(const float4*)(gA + k0 + 8);
        float4 f3 = *(const float4*)(gA + k0 + 12);
        uint4 pa0, pa1;
        pa0.x = pack2bf(f0.x, f0.y); pa0.y = pack2bf(f0.z, f0.w);
        pa0.z = pack2bf(f1.x, f1.y); pa0.w = pack2bf(f1.z, f1.w);
        pa1.x = pack2bf(f2.x, f2.y); pa1.y = pack2bf(f2.z, f2.w);
        pa1.z = pack2bf(f3.x, f3.y); pa1.w = pack2bf(f3.z, f3.w);
        // stage B: straight bf16 copy (L2-resident)
        uint4 b0 = *(const uint4*)(gB + k0);
        uint4 b1 = *(const uint4*)(gB + k0 + 8);
        ((uint4*)dA)[0] = pa0; ((uint4*)dA)[1] = pa1;
        ((uint4*)dB)[0] = b0;  ((uint4*)dB)[1] = b1;
        __syncthreads();

        bf16x8 af[2], bfm[8];
        #pragma unroll
        for (int mt = 0; mt < 2; mt++)
            af[mt] = *(const bf16x8*)&sA[(wv * 32 + mt * 16 + lr) * 40 + quad * 8];
        #pragma unroll
        for (int nt = 0; nt < 8; nt++)
            bfm[nt] = *(const bf16x8*)&sB[(nt * 16 + lr) * 40 + quad * 8];
        #pragma unroll
        for (int mt = 0; mt < 2; mt++)
            #pragma unroll
            for (int nt = 0; nt < 8; nt++)
                acc[mt][nt] = __builtin_amdgcn_mfma_f32_16x16x32_bf16(
                    af[mt], bfm[nt], acc[mt][nt], 0, 0, 0);
        __syncthreads();
    }

    // epilogue: tanh + We-weighted row reduction
    float part[2][4] = {{0.f, 0.f, 0.f, 0.f}, {0.f, 0.f, 0.f, 0.f}};
    #pragma unroll
    for (int nt = 0; nt < 8; nt++) {
        int col = nt * 16 + lr;
        float we = We[col];
        float q  = qp[(size_t)b * AD + col];
        #pragma unroll
        for (int mt = 0; mt < 2; mt++)
            #pragma unroll
            for (int r = 0; r < 4; r++) {
                float x = acc[mt][nt][r] + q;
                float e2 = __expf(2.0f * x);        // tanh(x)=1-2/(e^{2x}+1)
                float th = 1.0f - 2.0f / (e2 + 1.0f);
                part[mt][r] += we * th;
            }
    }
    #pragma unroll
    for (int mt = 0; mt < 2; mt++)
        #pragma unroll
        for (int r = 0; r < 4; r++) {
            float v = part[mt][r];
            v += __shfl_xor(v, 1); v += __shfl_xor(v, 2);
            v += __shfl_xor(v, 4); v += __shfl_xor(v, 8);
            if (lr == 0)
                energy[(size_t)m0 + wv * 32 + mt * 16 + quad * 4 + r] = v;
        }
}

// ---------------- block reductions (identical order to v1) ----------------
__device__ __forceinline__ float block_red_max(float v, float* sred) {
    #pragma unroll
    for (int m = 1; m < 64; m <<= 1) v = fmaxf(v, __shfl_xor(v, m));
    if ((threadIdx.x & 63) == 0) sred[threadIdx.x >> 6] = v;
    __syncthreads();
    float r = fmaxf(fmaxf(sred[0], sred[1]), fmaxf(sred[2], sred[3]));
    __syncthreads();
    return r;
}
__device__ __forceinline__ float block_red_sum(float v, float* sred) {
    #pragma unroll
    for (int m = 1; m < 64; m <<= 1) v += __shfl_xor(v, m);
    if ((threadIdx.x & 63) == 0) sred[threadIdx.x >> 6] = v;
    __syncthreads();
    float r = (sred[0] + sred[1]) + (sred[2] + sred[3]);
    __syncthreads();
    return r;
}

// ---------------- kernel 3: fused softmax + forward attn + context partial ----
// Grid 512 = 32 batches x 16 t-chunks. Every block for batch b redundantly
// recomputes the softmax/forward-reweight stats for the full T=2048 row
// (reads ~24 KB from L2/L3 -- negligible vs the 134 MB values stream), in the
// EXACT reduction order of the v1 softmax kernel (bit-identical fw). It then
// writes its own 128-wide fw chunk to d_out and accumulates its context
// partial from values. Removes the 32-block softmax kernel's serialization
// bubble, one launch, and one fw global round-trip.
__global__ __launch_bounds__(256) void ctx_fused_kernel(
    const float* __restrict__ energy, const float* __restrict__ prev,
    const int* __restrict__ mask, const float* __restrict__ values,
    float* __restrict__ fw, float* __restrict__ part)
{
    __shared__ float sred[4];
    __shared__ float sfw[2048];
    __shared__ float4 sacc[128];
    const int b = blockIdx.x >> 4, ts = blockIdx.x & 15;
    const int tid = threadIdx.x;
    const size_t base = (size_t)b * T_;

    // ---- replicated masked softmax (same order as v1 softmax kernel) ----
    float e[8];
    #pragma unroll
    for (int i = 0; i < 8; i++) {
        int t = tid + 256 * i;
        float ev = energy[base + t];
        if (mask[base + t] == 0) ev = -__builtin_inff();
        e[i] = ev;
    }
    float mx = e[0];
    #pragma unroll
    for (int i = 1; i < 8; i++) mx = fmaxf(mx, e[i]);
    mx = block_red_max(mx, sred);

    float ex[8]; float s = 0.f;
    #pragma unroll
    for (int i = 0; i < 8; i++) { ex[i] = __expf(e[i] - mx); s += ex[i]; }
    s = block_red_sum(s, sred);
    const float invS = 1.0f / s;

    float fwv[8]; float s2 = 0.f;
    #pragma unroll
    for (int i = 0; i < 8; i++) {
        int t = tid + 256 * i;
        float pv = prev[base + t];
        float pm = (t == 0) ? 0.f : prev[base + t - 1];
        float r = ex[i] * invS;
        fwv[i] = (t == 0) ? r : r * (pv + pm);
        s2 += fwv[i];
    }
    s2 = block_red_sum(s2, sred);
    const float invD = 1.0f / (s2 + 1e-8f);
    #pragma unroll
    for (int i = 0; i < 8; i++)
        sfw[tid + 256 * i] = fwv[i] * invD;
    __syncthreads();

    const int t0 = ts * 128;
    // own-chunk fw writeback (each chunk written exactly once across grid)
    if (tid < 128) fw[base + t0 + tid] = sfw[t0 + tid];

    // ---- context partial over own chunk ----
    const int d4 = tid & 127, tp = tid >> 7;
    const float* sf = &sfw[t0];
    const float4* vp = (const float4*)values + ((size_t)b * T_ + t0 + tp) * 128 + d4;
    float4 acc = {0.f, 0.f, 0.f, 0.f};
    #pragma unroll 8
    for (int i = 0; i < 64; i++) {
        float f = sf[tp + 2 * i];
        float4 v = vp[(size_t)i * 256];
        acc.x += f * v.x; acc.y += f * v.y; acc.z += f * v.z; acc.w += f * v.w;
    }
    if (tp) sacc[d4] = acc;
    __syncthreads();
    if (!tp) {
        float4 o = sacc[d4];
        o.x += acc.x; o.y += acc.y; o.z += acc.z; o.w += acc.w;
        ((float4*)part)[(size_t)blockIdx.x * 128 + d4] = o;
    }
}

// ---------------- kernel 4: reduce partials -> context ----------------
__global__ __launch_bounds__(256) void ctx_reduce_kernel(
    const float* __restrict__ part, float* __restrict__ ctx)
{
    const int idx = blockIdx.x * 256 + threadIdx.x;  // 0..16383
    const int b = idx >> 9, d = idx & 511;
    float s = 0.f;
    #pragma unroll
    for (int ts = 0; ts < 16; ts++)
        s += part[((size_t)(b * 16 + ts)) * 512 + d];
    ctx[idx] = s;
}

extern "C" void kernel_launch(void* const* d_in, const int* in_sizes, int n_in,
                              void* d_out, int out_size, void* d_ws, size_t ws_size,
                              hipStream_t stream) {
    const float* query  = (const float*)d_in[0];
    const float* keys   = (const float*)d_in[1];
    const float* values = (const float*)d_in[2];
    const float* prev   = (const float*)d_in[3];
    const int*   mask   = (const int*)d_in[4];
    const float* Wq     = (const float*)d_in[5];
    const float* Wk     = (const float*)d_in[6];
    const float* We     = (const float*)d_in[7];

    float* ctx = (float*)d_out;          // 32*512
    float* fw  = ctx + 32 * 512;         // 32*2048 (final fw only; energies in ws)

    float* wsf = (float*)d_ws;
    float* qp     = wsf;                                  // 4096 floats
    float* part   = wsf + 4096;                           // 16*32*512 = 262144 floats
    float* energy = wsf + 4096 + 262144;                  // 65536 floats
    unsigned short* WkT = (unsigned short*)(wsf + 4096 + 262144 + 65536);  // 65536 ushorts

    prep_kernel<<<dim3(64), dim3(256), 0, stream>>>(query, Wq, Wk, qp, WkT);
    energy_kernel<<<dim3(512), dim3(256), 0, stream>>>(keys, WkT, qp, We, energy);
    ctx_fused_kernel<<<dim3(512), dim3(256), 0, stream>>>(energy, prev, mask, values, fw, part);
    ctx_reduce_kernel<<<dim3(64), dim3(256), 0, stream>>>(part, ctx);
}